// Round 1
// baseline (67168.726 us; speedup 1.0000x reference)
//
#include <hip/hip_runtime.h>
#include <hip/hip_bf16.h>
#include <cstdint>

#define T_STEPS 512
#define BATCH   64
#define XDIM    64
#define HDIM    1024
#define YDIM    64

typedef unsigned short ushort_t;
typedef uint32_t u32;

// ---------- helpers ----------
__device__ __forceinline__ void unpack8(const uint4 v, float* f) {
  f[0] = __uint_as_float(v.x << 16);
  f[1] = __uint_as_float(v.x & 0xffff0000u);
  f[2] = __uint_as_float(v.y << 16);
  f[3] = __uint_as_float(v.y & 0xffff0000u);
  f[4] = __uint_as_float(v.z << 16);
  f[5] = __uint_as_float(v.z & 0xffff0000u);
  f[6] = __uint_as_float(v.w << 16);
  f[7] = __uint_as_float(v.w & 0xffff0000u);
}

__device__ __forceinline__ ushort_t f2bf(float x) {
  u32 u = __float_as_uint(x);
  u32 r = (u + 0x7fffu + ((u >> 16) & 1u)) >> 16;  // round-nearest-even
  return (ushort_t)r;
}

__device__ __forceinline__ float sigm(float x) { return 1.0f / (1.0f + __expf(-x)); }

__device__ __forceinline__ void dot4(float& acc, const float* a, const float4 w) {
  acc = fmaf(a[0], w.x, acc);
  acc = fmaf(a[1], w.y, acc);
  acc = fmaf(a[2], w.z, acc);
  acc = fmaf(a[3], w.w, acc);
}

// ---------- encoder: enc_out[t*B+b][h] = tanh(x@enc_w.T + enc_b), bf16 out ----------
// grid 32768 = 2048 row-tiles(16 rows) x 16 col-tiles(64 cols); block 256
__global__ __launch_bounds__(256) void enc_kernel(
    const float* __restrict__ x, const float* __restrict__ enc_w,
    const float* __restrict__ enc_b, ushort_t* __restrict__ enc_out)
{
  const int lane = threadIdx.x & 63;
  const int wv   = threadIdx.x >> 6;
  const int cb = blockIdx.x & 15;
  const int rb = blockIdx.x >> 4;
  const int j  = cb * 64 + lane;
  const int r0 = rb * 16 + wv * 4;
  const float* wrow = enc_w + (size_t)j * XDIM;
  const float* xr   = x + (size_t)r0 * XDIM;
  float acc[4] = {0.f, 0.f, 0.f, 0.f};
#pragma unroll
  for (int k = 0; k < XDIM; k += 4) {
    float4 w4 = *(const float4*)(wrow + k);
#pragma unroll
    for (int rr = 0; rr < 4; ++rr) {
      float4 xv = *(const float4*)(xr + rr * XDIM + k);
      acc[rr] = fmaf(xv.x, w4.x, acc[rr]);
      acc[rr] = fmaf(xv.y, w4.y, acc[rr]);
      acc[rr] = fmaf(xv.z, w4.z, acc[rr]);
      acc[rr] = fmaf(xv.w, w4.w, acc[rr]);
    }
  }
  float b = enc_b[j];
#pragma unroll
  for (int rr = 0; rr < 4; ++rr)
    enc_out[(size_t)(r0 + rr) * HDIM + j] = f2bf(tanhf(acc[rr] + b));
}

// ---------- one GRU cell output column j for all lanes(=batch) ----------
template <bool A1BF>
__device__ __forceinline__ void gru_stage(
    const void* __restrict__ a1ptr,   // input row (bf16 if A1BF else f32)
    const float* __restrict__ a2row,  // recurrent h_prev row (f32)
    const float* __restrict__ wi, const float* __restrict__ wh,   // layer bases
    const float* __restrict__ bi, const float* __restrict__ bh,   // layer biases
    int j,
    float* __restrict__ hout_row,     // f32 h_new row base
    ushort_t* __restrict__ hall_row)  // optional bf16 row base (may be null)
{
  const float* wir = wi + (size_t)j * HDIM;
  const float* wiz = wir + (size_t)HDIM * HDIM;
  const float* win = wiz + (size_t)HDIM * HDIM;
  const float* whr = wh + (size_t)j * HDIM;
  const float* whz = whr + (size_t)HDIM * HDIM;
  const float* whn = whz + (size_t)HDIM * HDIM;

  float ai_r = 0.f, ai_z = 0.f, ai_n = 0.f;
  float ah_r = 0.f, ah_z = 0.f, ah_n = 0.f;

#pragma unroll 2
  for (int k = 0; k < HDIM; k += 8) {
    float a1f[8];
    if (A1BF) {
      uint4 v = *(const uint4*)((const ushort_t*)a1ptr + k);
      unpack8(v, a1f);
    } else {
      const float* p = (const float*)a1ptr + k;
      float4 u0 = *(const float4*)p;
      float4 u1 = *(const float4*)(p + 4);
      a1f[0] = u0.x; a1f[1] = u0.y; a1f[2] = u0.z; a1f[3] = u0.w;
      a1f[4] = u1.x; a1f[5] = u1.y; a1f[6] = u1.z; a1f[7] = u1.w;
    }
    float a2f[8];
    {
      float4 u0 = *(const float4*)(a2row + k);
      float4 u1 = *(const float4*)(a2row + k + 4);
      a2f[0] = u0.x; a2f[1] = u0.y; a2f[2] = u0.z; a2f[3] = u0.w;
      a2f[4] = u1.x; a2f[5] = u1.y; a2f[6] = u1.z; a2f[7] = u1.w;
    }
#pragma unroll
    for (int h = 0; h < 8; h += 4) {
      dot4(ai_r, a1f + h, *(const float4*)(wir + k + h));
      dot4(ai_z, a1f + h, *(const float4*)(wiz + k + h));
      dot4(ai_n, a1f + h, *(const float4*)(win + k + h));
      dot4(ah_r, a2f + h, *(const float4*)(whr + k + h));
      dot4(ah_z, a2f + h, *(const float4*)(whz + k + h));
      dot4(ah_n, a2f + h, *(const float4*)(whn + k + h));
    }
  }

  float gi_r = ai_r + bi[j];
  float gi_z = ai_z + bi[HDIM + j];
  float gi_n = ai_n + bi[2 * HDIM + j];
  float gh_r = ah_r + bh[j];
  float gh_z = ah_z + bh[HDIM + j];
  float gh_n = ah_n + bh[2 * HDIM + j];

  float r = sigm(gi_r + gh_r);
  float z = sigm(gi_z + gh_z);
  float n = tanhf(gi_n + r * gh_n);
  float hp = a2row[j];
  float hv = (1.0f - z) * n + z * hp;

  hout_row[j] = hv;
  if (hall_row) hall_row[j] = f2bf(hv);
}

// ---------- pipelined step: blocks 0..255 -> L0(t=s); blocks 256..511 -> L1(t=s-1) ----------
// wave = one output column j (weight loads wave-uniform), lane = batch index
__global__ __launch_bounds__(256) void step_kernel(
    int s, const ushort_t* __restrict__ enc_out,
    const float* __restrict__ w_ih, const float* __restrict__ w_hh,
    const float* __restrict__ b_ih, const float* __restrict__ b_hh,
    float* __restrict__ h0_buf, float* __restrict__ h1_buf,
    ushort_t* __restrict__ h1_all)
{
  const int lane = threadIdx.x & 63;
  const int wv   = threadIdx.x >> 6;
  const int blk  = blockIdx.x;

  if (blk < 256) {
    if (s >= T_STEPS) return;
    const int j = __builtin_amdgcn_readfirstlane(blk * 4 + wv);
    const ushort_t* a1 = enc_out + ((size_t)s * BATCH + lane) * HDIM;
    const float* a2 = h0_buf + (size_t)((s + 1) & 1) * (BATCH * HDIM) + (size_t)lane * HDIM;
    float* hout     = h0_buf + (size_t)(s & 1)       * (BATCH * HDIM) + (size_t)lane * HDIM;
    gru_stage<true>(a1, a2, w_ih, w_hh, b_ih, b_hh, j, hout, (ushort_t*)nullptr);
  } else {
    if (s < 1) return;
    const int u = s - 1;
    const int j = __builtin_amdgcn_readfirstlane((blk - 256) * 4 + wv);
    const float* a1 = h0_buf + (size_t)(u & 1) * (BATCH * HDIM) + (size_t)lane * HDIM;   // h0(u)
    const float* a2 = h1_buf + (size_t)(s & 1) * (BATCH * HDIM) + (size_t)lane * HDIM;   // h1(u-1)
    float* hout     = h1_buf + (size_t)(u & 1) * (BATCH * HDIM) + (size_t)lane * HDIM;
    ushort_t* hall  = h1_all + (size_t)u * (BATCH * HDIM) + (size_t)lane * HDIM;
    gru_stage<false>(a1, a2, w_ih + 3 * HDIM * HDIM, w_hh + 3 * HDIM * HDIM,
                     b_ih + 3 * HDIM, b_hh + 3 * HDIM, j, hout, hall);
  }
}

// ---------- decoder: rnn_out = tanh(h1_all @ dec_w.T + dec_b), bf16 out ----------
// grid 8192 = 512 row-tiles(64) x 16 col-tiles(64); block 256; wave handles 16 cols
__global__ __launch_bounds__(256) void dec_kernel(
    const ushort_t* __restrict__ h1_all, const float* __restrict__ dec_w,
    const float* __restrict__ dec_b, ushort_t* __restrict__ rnn_out)
{
  const int lane = threadIdx.x & 63;
  const int wv   = threadIdx.x >> 6;
  const int cb = blockIdx.x & 15;
  const int rb = blockIdx.x >> 4;
  const int row = rb * 64 + lane;
  const int j0  = cb * 64 + wv * 16;
  const ushort_t* a = h1_all + (size_t)row * HDIM;
  float acc[16];
#pragma unroll
  for (int c = 0; c < 16; ++c) acc[c] = 0.f;

#pragma unroll 1
  for (int k = 0; k < HDIM; k += 8) {
    float af[8];
    uint4 v = *(const uint4*)(a + k);
    unpack8(v, af);
#pragma unroll
    for (int c = 0; c < 16; ++c) {
      const float* wr = dec_w + (size_t)(j0 + c) * HDIM + k;
      dot4(acc[c], af,     *(const float4*)wr);
      dot4(acc[c], af + 4, *(const float4*)(wr + 4));
    }
  }
#pragma unroll
  for (int c = 0; c < 16; ++c) {
    float vq = tanhf(acc[c] + dec_b[j0 + c]);
    rnn_out[(size_t)row * HDIM + j0 + c] = f2bf(vq);
  }
}

// ---------- heads: mean/var; grid 512 row-tiles(64); block 256; wave handles 32 outputs ----------
__global__ __launch_bounds__(256) void head_kernel(
    const ushort_t* __restrict__ rnn_out,
    const float* __restrict__ exp_w, const float* __restrict__ exp_b,
    const float* __restrict__ log_w, const float* __restrict__ log_b,
    float* __restrict__ out)
{
  const int lane = threadIdx.x & 63;
  const int wv   = threadIdx.x >> 6;
  const int row = blockIdx.x * 64 + lane;
  const int c0  = wv * 32;                       // 0,32 -> mean; 64,96 -> var
  const ushort_t* a = rnn_out + (size_t)row * HDIM;
  const float* wmat = (c0 < 64) ? exp_w : log_w;
  const int cc0 = c0 & 63;

  float acc[32];
#pragma unroll
  for (int i = 0; i < 32; ++i) acc[i] = 0.f;

#pragma unroll 1
  for (int k = 0; k < HDIM; k += 8) {
    float af[8];
    uint4 v = *(const uint4*)(a + k);
    unpack8(v, af);
#pragma unroll
    for (int i = 0; i < 32; ++i) {
      const float* wr = wmat + (size_t)(cc0 + i) * HDIM + k;
      dot4(acc[i], af,     *(const float4*)wr);
      dot4(acc[i], af + 4, *(const float4*)(wr + 4));
    }
  }

  if (c0 < 64) {
#pragma unroll
    for (int i = 0; i < 32; ++i) {
      int y = cc0 + i;
      out[(size_t)row * YDIM + y] = acc[i] + exp_b[y];
    }
  } else {
#pragma unroll
    for (int i = 0; i < 32; ++i) {
      int y = cc0 + i;
      out[(size_t)(T_STEPS * BATCH * YDIM) + (size_t)row * YDIM + y] = expf(acc[i] + log_b[y]);
    }
  }
}

// ---------- host ----------
extern "C" void kernel_launch(void* const* d_in, const int* in_sizes, int n_in,
                              void* d_out, int out_size, void* d_ws, size_t ws_size,
                              hipStream_t stream) {
  (void)in_sizes; (void)n_in; (void)out_size; (void)ws_size;
  const float* x     = (const float*)d_in[0];
  const float* enc_w = (const float*)d_in[1];
  const float* enc_b = (const float*)d_in[2];
  const float* w_ih  = (const float*)d_in[3];
  const float* w_hh  = (const float*)d_in[4];
  const float* b_ih  = (const float*)d_in[5];
  const float* b_hh  = (const float*)d_in[6];
  const float* dec_w = (const float*)d_in[7];
  const float* dec_b = (const float*)d_in[8];
  const float* exp_w = (const float*)d_in[9];
  const float* exp_b = (const float*)d_in[10];
  const float* log_w = (const float*)d_in[11];
  const float* log_b = (const float*)d_in[12];
  float* out = (float*)d_out;

  char* ws = (char*)d_ws;
  float*    h0_buf  = (float*)ws;                                   // 2*64*1024 f32 = 512 KB
  float*    h1_buf  = (float*)(ws + 524288);                        // 512 KB
  ushort_t* enc_out = (ushort_t*)(ws + 1048576);                    // 32768*1024 bf16 = 64 MB (reused as rnn_out)
  ushort_t* h1_all  = (ushort_t*)(ws + 1048576 + 67108864);         // 64 MB

  // zero recurrent-state double buffers (needed fresh every call)
  hipMemsetAsync(ws, 0, 1048576, stream);

  enc_kernel<<<32768, 256, 0, stream>>>(x, enc_w, enc_b, enc_out);

  for (int s = 0; s <= T_STEPS; ++s)
    step_kernel<<<512, 256, 0, stream>>>(s, enc_out, w_ih, w_hh, b_ih, b_hh,
                                         h0_buf, h1_buf, h1_all);

  dec_kernel<<<8192, 256, 0, stream>>>(h1_all, dec_w, dec_b, enc_out /* rnn_out */);
  head_kernel<<<512, 256, 0, stream>>>(enc_out, exp_w, exp_b, log_w, log_b, out);
}

// Round 2
// 63576.935 us; speedup vs baseline: 1.0565x; 1.0565x over previous
//
#include <hip/hip_runtime.h>
#include <hip/hip_bf16.h>
#include <hip/hip_cooperative_groups.h>
#include <cstdint>

namespace cg = cooperative_groups;

#define T_STEPS 512
#define BATCH   64
#define XDIM    64
#define HDIM    1024
#define YDIM    64

typedef unsigned short ushort_t;
typedef uint32_t u32;
typedef __attribute__((ext_vector_type(8))) short short8;
typedef __attribute__((ext_vector_type(4))) float f32x4;

// ---------- helpers ----------
__device__ __forceinline__ void unpack8(const uint4 v, float* f) {
  f[0] = __uint_as_float(v.x << 16);
  f[1] = __uint_as_float(v.x & 0xffff0000u);
  f[2] = __uint_as_float(v.y << 16);
  f[3] = __uint_as_float(v.y & 0xffff0000u);
  f[4] = __uint_as_float(v.z << 16);
  f[5] = __uint_as_float(v.z & 0xffff0000u);
  f[6] = __uint_as_float(v.w << 16);
  f[7] = __uint_as_float(v.w & 0xffff0000u);
}

__device__ __forceinline__ ushort_t f2bf(float x) {
  u32 u = __float_as_uint(x);
  u32 r = (u + 0x7fffu + ((u >> 16) & 1u)) >> 16;  // round-nearest-even
  return (ushort_t)r;
}

__device__ __forceinline__ float sigm(float x) { return 1.0f / (1.0f + expf(-x)); }

__device__ __forceinline__ void dot4(float& acc, const float* a, const float4 w) {
  acc = fmaf(a[0], w.x, acc);
  acc = fmaf(a[1], w.y, acc);
  acc = fmaf(a[2], w.z, acc);
  acc = fmaf(a[3], w.w, acc);
}

// ---------- encoder: enc_out[t*B+b][h] = tanh(x@enc_w.T + enc_b), bf16 out ----------
__global__ __launch_bounds__(256) void enc_kernel(
    const float* __restrict__ x, const float* __restrict__ enc_w,
    const float* __restrict__ enc_b, ushort_t* __restrict__ enc_out)
{
  const int lane = threadIdx.x & 63;
  const int wv   = threadIdx.x >> 6;
  const int cb = blockIdx.x & 15;
  const int rb = blockIdx.x >> 4;
  const int j  = cb * 64 + lane;
  const int r0 = rb * 16 + wv * 4;
  const float* wrow = enc_w + (size_t)j * XDIM;
  const float* xr   = x + (size_t)r0 * XDIM;
  float acc[4] = {0.f, 0.f, 0.f, 0.f};
#pragma unroll
  for (int k = 0; k < XDIM; k += 4) {
    float4 w4 = *(const float4*)(wrow + k);
#pragma unroll
    for (int rr = 0; rr < 4; ++rr) {
      float4 xv = *(const float4*)(xr + rr * XDIM + k);
      acc[rr] = fmaf(xv.x, w4.x, acc[rr]);
      acc[rr] = fmaf(xv.y, w4.y, acc[rr]);
      acc[rr] = fmaf(xv.z, w4.z, acc[rr]);
      acc[rr] = fmaf(xv.w, w4.w, acc[rr]);
    }
  }
  float b = enc_b[j];
#pragma unroll
  for (int rr = 0; rr < 4; ++rr)
    enc_out[(size_t)(r0 + rr) * HDIM + j] = f2bf(tanhf(acc[rr] + b));
}

// ---------- persistent recurrent kernel ----------
// 256 blocks x 512 threads. Block b: layer = b>>7, owns h-cols j0 = (b&127)*8 .. +7.
// Wave (of 8): mp = w&1 (m-pair), g = (w>>1)&1 (0: ih/A1, 1: hh/A2), kh = w>>2 (K half).
// B-tiles per wave: tl=0 -> cols [gate_r(8) | gate_z(8)]; tl=1 -> [gate_n(8) | zero(8)].
// Weights live in VGPRs for all 512 steps. One grid.sync per step.
__global__ __launch_bounds__(512, 2) void rnn_persist(
    const ushort_t* __restrict__ enc_out,
    const float* __restrict__ w_ih, const float* __restrict__ w_hh,
    const float* __restrict__ b_ih, const float* __restrict__ b_hh,
    ushort_t* __restrict__ h0s, ushort_t* __restrict__ h1s,
    ushort_t* __restrict__ h1_all)
{
  __shared__ float lds_part[32 * 256];  // 32 partial C tiles (64 lanes x f32x4) = 32 KB

  const int tid  = threadIdx.x;
  const int lane = tid & 63;
  const int wid  = tid >> 6;
  const int bid  = blockIdx.x;
  const int layer = bid >> 7;
  const int j0    = (bid & 127) * 8;
  const int mp = wid & 1, g = (wid >> 1) & 1, kh = wid >> 2;
  const int col = lane & 15, kgrp = lane >> 4;

  // ---- one-time: weights -> register B-fragments (bf16) ----
  const float* wsrc = (g ? w_hh : w_ih) + (size_t)layer * 3 * HDIM * HDIM;
  short8 bfr[2][16];
#pragma unroll
  for (int tl = 0; tl < 2; ++tl) {
#pragma unroll
    for (int ko = 0; ko < 16; ++ko) {
      const int k = kh * 512 + ko * 32 + kgrp * 8;
      short8 v;
      if (tl == 0) {
        const int row = (col < 8) ? (j0 + col) : (HDIM + j0 + col - 8);
        const float* p = wsrc + (size_t)row * HDIM + k;
#pragma unroll
        for (int e = 0; e < 8; ++e) v[e] = (short)f2bf(p[e]);
      } else if (col < 8) {
        const int row = 2 * HDIM + j0 + col;
        const float* p = wsrc + (size_t)row * HDIM + k;
#pragma unroll
        for (int e = 0; e < 8; ++e) v[e] = (short)f2bf(p[e]);
      } else {
#pragma unroll
        for (int e = 0; e < 8; ++e) v[e] = 0;
      }
      bfr[tl][ko] = v;
    }
  }

  // ---- one-time: biases (used by elementwise waves 0-3; same formula all waves) ----
  float bA = 0.f, bB = 0.f, bC = 0.f;
  {
    const float* bi = b_ih + layer * 3 * HDIM;
    const float* bh = b_hh + layer * 3 * HDIM;
    if (col < 8) {
      const int j = j0 + col;
      bA = bi[j] + bh[j];             // r-gate combined bias
      bB = bi[2 * HDIM + j];          // i_n bias
      bC = bh[2 * HDIM + j];          // h_n bias
    } else {
      const int j = j0 + col - 8;
      bA = bi[HDIM + j] + bh[HDIM + j];  // z-gate combined bias
    }
  }

  f32x4 hp = {0.f, 0.f, 0.f, 0.f};  // own h-state, fp32, in regs (waves 0-3)

  cg::grid_group grid = cg::this_grid();
  const bool isL1 = (layer == 1);

  for (int s = 0; s <= T_STEPS; ++s) {
    const bool active = isL1 ? (s >= 1) : (s < T_STEPS);
    if (active) {
      const int t = isL1 ? (s - 1) : s;
      const ushort_t* A1 = isL1 ? (h0s + ((s + 1) & 1) * (BATCH * HDIM))
                                : (enc_out + (size_t)t * (BATCH * HDIM));
      const ushort_t* A2 = isL1 ? (h1s + (s & 1) * (BATCH * HDIM))
                                : (h0s + ((s + 1) & 1) * (BATCH * HDIM));
      const ushort_t* A = g ? A2 : A1;

      f32x4 acc00 = {0,0,0,0}, acc01 = {0,0,0,0}, acc10 = {0,0,0,0}, acc11 = {0,0,0,0};
      const ushort_t* Arow0 = A + (size_t)(mp * 32 + col) * HDIM + kh * 512 + kgrp * 8;
      const ushort_t* Arow1 = Arow0 + 16 * HDIM;
#pragma unroll
      for (int ko = 0; ko < 16; ++ko) {
        const short8 a0 = *(const short8*)(Arow0 + ko * 32);
        const short8 a1 = *(const short8*)(Arow1 + ko * 32);
        acc00 = __builtin_amdgcn_mfma_f32_16x16x32_bf16(a0, bfr[0][ko], acc00, 0, 0, 0);
        acc01 = __builtin_amdgcn_mfma_f32_16x16x32_bf16(a0, bfr[1][ko], acc01, 0, 0, 0);
        acc10 = __builtin_amdgcn_mfma_f32_16x16x32_bf16(a1, bfr[0][ko], acc10, 0, 0, 0);
        acc11 = __builtin_amdgcn_mfma_f32_16x16x32_bf16(a1, bfr[1][ko], acc11, 0, 0, 0);
      }
      // publish partial tiles: tile idx = wid*4 + im*2 + tl
      const int base = (wid * 4) * 256 + lane * 4;
      *(f32x4*)&lds_part[base        ] = acc00;
      *(f32x4*)&lds_part[base + 256  ] = acc01;
      *(f32x4*)&lds_part[base + 512  ] = acc10;
      *(f32x4*)&lds_part[base + 768  ] = acc11;
    }
    __syncthreads();

    if (active && wid < 4) {
      const int m = wid, mpe = m >> 1, ime = m & 1;
      // source tile base for (g,kh): wave (kh<<2)|(g<<1)|mpe, sub = ime*2 + tl
      const int i00 = ((0 * 4 + 0 * 2 + mpe) * 4 + ime * 2);  // ih, kh=0
      const int i01 = ((1 * 4 + 0 * 2 + mpe) * 4 + ime * 2);  // ih, kh=1
      const int i10 = ((0 * 4 + 1 * 2 + mpe) * 4 + ime * 2);  // hh, kh=0
      const int i11 = ((1 * 4 + 1 * 2 + mpe) * 4 + ime * 2);  // hh, kh=1
      const int lo = lane * 4;
      f32x4 girz = *(f32x4*)&lds_part[i00 * 256 + lo] + *(f32x4*)&lds_part[i01 * 256 + lo];
      f32x4 gin  = *(f32x4*)&lds_part[(i00 + 1) * 256 + lo] + *(f32x4*)&lds_part[(i01 + 1) * 256 + lo];
      f32x4 ghrz = *(f32x4*)&lds_part[i10 * 256 + lo] + *(f32x4*)&lds_part[i11 * 256 + lo];
      f32x4 ghn  = *(f32x4*)&lds_part[(i10 + 1) * 256 + lo] + *(f32x4*)&lds_part[(i11 + 1) * 256 + lo];

      ushort_t* hdst = isL1 ? (h1s + ((s + 1) & 1) * (BATCH * HDIM))
                            : (h0s + (s & 1) * (BATCH * HDIM));
      ushort_t* hall = isL1 ? (h1_all + (size_t)(s - 1) * (BATCH * HDIM)) : (ushort_t*)0;

#pragma unroll
      for (int e = 0; e < 4; ++e) {
        const float rz = sigm(girz[e] + ghrz[e] + bA);               // lo: r, hi: z
        const float nv = tanhf(gin[e] + bB + rz * (ghn[e] + bC));    // valid in lo lanes
        const float zv = __shfl_xor(rz, 8);                          // z arrives at lo lanes
        const float h  = (1.f - zv) * nv + zv * hp[e];
        if (col < 8) {
          hp[e] = h;
          const int b = m * 16 + kgrp * 4 + e;
          const ushort_t hb = f2bf(h);
          hdst[b * HDIM + j0 + col] = hb;
          if (hall) hall[b * HDIM + j0 + col] = hb;
        }
      }
    }
    __threadfence();
    grid.sync();
    __threadfence();
  }
}

// ---------- decoder: rnn_out = tanh(h1_all @ dec_w.T + dec_b), bf16 out ----------
__global__ __launch_bounds__(256) void dec_kernel(
    const ushort_t* __restrict__ h1_all, const float* __restrict__ dec_w,
    const float* __restrict__ dec_b, ushort_t* __restrict__ rnn_out)
{
  const int lane = threadIdx.x & 63;
  const int wv   = threadIdx.x >> 6;
  const int cb = blockIdx.x & 15;
  const int rb = blockIdx.x >> 4;
  const int row = rb * 64 + lane;
  const int j0  = cb * 64 + wv * 16;
  const ushort_t* a = h1_all + (size_t)row * HDIM;
  float acc[16];
#pragma unroll
  for (int c = 0; c < 16; ++c) acc[c] = 0.f;

#pragma unroll 1
  for (int k = 0; k < HDIM; k += 8) {
    float af[8];
    uint4 v = *(const uint4*)(a + k);
    unpack8(v, af);
#pragma unroll
    for (int c = 0; c < 16; ++c) {
      const float* wr = dec_w + (size_t)(j0 + c) * HDIM + k;
      dot4(acc[c], af,     *(const float4*)wr);
      dot4(acc[c], af + 4, *(const float4*)(wr + 4));
    }
  }
#pragma unroll
  for (int c = 0; c < 16; ++c) {
    float vq = tanhf(acc[c] + dec_b[j0 + c]);
    rnn_out[(size_t)row * HDIM + j0 + c] = f2bf(vq);
  }
}

// ---------- heads: mean/var ----------
__global__ __launch_bounds__(256) void head_kernel(
    const ushort_t* __restrict__ rnn_out,
    const float* __restrict__ exp_w, const float* __restrict__ exp_b,
    const float* __restrict__ log_w, const float* __restrict__ log_b,
    float* __restrict__ out)
{
  const int lane = threadIdx.x & 63;
  const int wv   = threadIdx.x >> 6;
  const int row = blockIdx.x * 64 + lane;
  const int c0  = wv * 32;
  const ushort_t* a = rnn_out + (size_t)row * HDIM;
  const float* wmat = (c0 < 64) ? exp_w : log_w;
  const int cc0 = c0 & 63;

  float acc[32];
#pragma unroll
  for (int i = 0; i < 32; ++i) acc[i] = 0.f;

#pragma unroll 1
  for (int k = 0; k < HDIM; k += 8) {
    float af[8];
    uint4 v = *(const uint4*)(a + k);
    unpack8(v, af);
#pragma unroll
    for (int i = 0; i < 32; ++i) {
      const float* wr = wmat + (size_t)(cc0 + i) * HDIM + k;
      dot4(acc[i], af,     *(const float4*)wr);
      dot4(acc[i], af + 4, *(const float4*)(wr + 4));
    }
  }

  if (c0 < 64) {
#pragma unroll
    for (int i = 0; i < 32; ++i) {
      int y = cc0 + i;
      out[(size_t)row * YDIM + y] = acc[i] + exp_b[y];
    }
  } else {
#pragma unroll
    for (int i = 0; i < 32; ++i) {
      int y = cc0 + i;
      out[(size_t)(T_STEPS * BATCH * YDIM) + (size_t)row * YDIM + y] = expf(acc[i] + log_b[y]);
    }
  }
}

// ---------- host ----------
extern "C" void kernel_launch(void* const* d_in, const int* in_sizes, int n_in,
                              void* d_out, int out_size, void* d_ws, size_t ws_size,
                              hipStream_t stream) {
  (void)in_sizes; (void)n_in; (void)out_size; (void)ws_size;
  const float* x     = (const float*)d_in[0];
  const float* enc_w = (const float*)d_in[1];
  const float* enc_b = (const float*)d_in[2];
  const float* w_ih  = (const float*)d_in[3];
  const float* w_hh  = (const float*)d_in[4];
  const float* b_ih  = (const float*)d_in[5];
  const float* b_hh  = (const float*)d_in[6];
  const float* dec_w = (const float*)d_in[7];
  const float* dec_b = (const float*)d_in[8];
  const float* exp_w = (const float*)d_in[9];
  const float* exp_b = (const float*)d_in[10];
  const float* log_w = (const float*)d_in[11];
  const float* log_b = (const float*)d_in[12];
  float* out = (float*)d_out;

  char* ws = (char*)d_ws;
  ushort_t* h0s     = (ushort_t*)ws;                          // 2 x [64][1024] bf16 = 256 KB
  ushort_t* h1s     = (ushort_t*)(ws + 262144);               // 256 KB
  ushort_t* enc_out = (ushort_t*)(ws + 524288);               // 64 MB (reused as rnn_out)
  ushort_t* h1_all  = (ushort_t*)(ws + 524288 + 67108864);    // 64 MB

  hipMemsetAsync(ws, 0, 524288, stream);  // zero h-state double buffers

  enc_kernel<<<32768, 256, 0, stream>>>(x, enc_w, enc_b, enc_out);

  {
    void* args[8];
    args[0] = (void*)&enc_out;
    args[1] = (void*)&w_ih;
    args[2] = (void*)&w_hh;
    args[3] = (void*)&b_ih;
    args[4] = (void*)&b_hh;
    args[5] = (void*)&h0s;
    args[6] = (void*)&h1s;
    args[7] = (void*)&h1_all;
    hipLaunchCooperativeKernel((const void*)rnn_persist, dim3(256), dim3(512),
                               args, 0, stream);
  }

  dec_kernel<<<8192, 256, 0, stream>>>(h1_all, dec_w, dec_b, enc_out /* rnn_out */);
  head_kernel<<<512, 256, 0, stream>>>(enc_out, exp_w, exp_b, log_w, log_b, out);
}

// Round 3
// 13263.016 us; speedup vs baseline: 5.0644x; 4.7936x over previous
//
#include <hip/hip_runtime.h>
#include <hip/hip_bf16.h>
#include <cstdint>

#define T_STEPS 512
#define BATCH   64
#define XDIM    64
#define HDIM    1024
#define YDIM    64

typedef unsigned short ushort_t;
typedef uint32_t u32;
typedef __attribute__((ext_vector_type(8))) short short8;
typedef __attribute__((ext_vector_type(4))) float f32x4;

// ---------- helpers ----------
__device__ __forceinline__ void unpack8(const uint4 v, float* f) {
  f[0] = __uint_as_float(v.x << 16);
  f[1] = __uint_as_float(v.x & 0xffff0000u);
  f[2] = __uint_as_float(v.y << 16);
  f[3] = __uint_as_float(v.y & 0xffff0000u);
  f[4] = __uint_as_float(v.z << 16);
  f[5] = __uint_as_float(v.z & 0xffff0000u);
  f[6] = __uint_as_float(v.w << 16);
  f[7] = __uint_as_float(v.w & 0xffff0000u);
}

__device__ __forceinline__ ushort_t f2bf(float x) {
  u32 u = __float_as_uint(x);
  u32 r = (u + 0x7fffu + ((u >> 16) & 1u)) >> 16;  // round-nearest-even
  return (ushort_t)r;
}

__device__ __forceinline__ float sigm(float x) { return 1.0f / (1.0f + expf(-x)); }

__device__ __forceinline__ void dot4(float& acc, const float* a, const float4 w) {
  acc = fmaf(a[0], w.x, acc);
  acc = fmaf(a[1], w.y, acc);
  acc = fmaf(a[2], w.z, acc);
  acc = fmaf(a[3], w.w, acc);
}

// ---------- encoder: ench1[t*B+b][h] = tanh(x@enc_w.T + enc_b), bf16 ----------
__global__ __launch_bounds__(256) void enc_kernel(
    const float* __restrict__ x, const float* __restrict__ enc_w,
    const float* __restrict__ enc_b, ushort_t* __restrict__ enc_out)
{
  const int lane = threadIdx.x & 63;
  const int wv   = threadIdx.x >> 6;
  const int cb = blockIdx.x & 15;
  const int rb = blockIdx.x >> 4;
  const int j  = cb * 64 + lane;
  const int r0 = rb * 16 + wv * 4;
  const float* wrow = enc_w + (size_t)j * XDIM;
  const float* xr   = x + (size_t)r0 * XDIM;
  float acc[4] = {0.f, 0.f, 0.f, 0.f};
#pragma unroll
  for (int k = 0; k < XDIM; k += 4) {
    float4 w4 = *(const float4*)(wrow + k);
#pragma unroll
    for (int rr = 0; rr < 4; ++rr) {
      float4 xv = *(const float4*)(xr + rr * XDIM + k);
      acc[rr] = fmaf(xv.x, w4.x, acc[rr]);
      acc[rr] = fmaf(xv.y, w4.y, acc[rr]);
      acc[rr] = fmaf(xv.z, w4.z, acc[rr]);
      acc[rr] = fmaf(xv.w, w4.w, acc[rr]);
    }
  }
  float b = enc_b[j];
#pragma unroll
  for (int rr = 0; rr < 4; ++rr)
    enc_out[(size_t)(r0 + rr) * HDIM + j] = f2bf(tanhf(acc[rr] + b));
}

// ---------- weight fragment pre-pack ----------
// chunk c = bid*128 + g*64 + kh*32 + tl*16 + ko  (matches consumer indexing)
// 32768 chunks, each 64 lanes x short8 (1 KB). Total 32 MB.
__global__ __launch_bounds__(256) void wprep_kernel(
    const float* __restrict__ w_ih, const float* __restrict__ w_hh,
    ushort_t* __restrict__ wfrag)
{
  const int lane = threadIdx.x & 63;
  const int wv   = threadIdx.x >> 6;
  const int c    = blockIdx.x * 4 + wv;
  const int ko = c & 15;
  const int tl = (c >> 4) & 1;
  const int kh = (c >> 5) & 1;
  const int g  = (c >> 6) & 1;
  const int bid = c >> 7;           // 0..255
  const int layer = bid >> 7;
  const int j0 = (bid & 127) * 8;
  const int col = lane & 15, kgrp = lane >> 4;
  const int k = kh * 512 + ko * 32 + kgrp * 8;

  short8 v;
  const bool zero = (tl == 1) && (col >= 8);
  if (!zero) {
    int row;
    if (tl == 0) row = (col < 8) ? (j0 + col) : (HDIM + j0 + col - 8);
    else         row = 2 * HDIM + j0 + col;
    const float* src = (g ? w_hh : w_ih) + (size_t)layer * 3 * HDIM * HDIM
                     + (size_t)row * HDIM + k;
#pragma unroll
    for (int e = 0; e < 8; ++e) v[e] = (short)f2bf(src[e]);
  } else {
#pragma unroll
    for (int e = 0; e < 8; ++e) v[e] = 0;
  }
  *(short8*)(wfrag + (size_t)c * 512 + lane * 8) = v;
}

// ---------- per-step kernel: blocks 0..127 -> L0(t=s); 128..255 -> L1(t=s-1) ----------
// Block owns 8 h-cols. Wave: mp=wid&1 (m-pair), g=(wid>>1)&1 (ih/hh), kh=wid>>2 (K half).
__global__ __launch_bounds__(512, 1) void step_kernel(
    int s, const ushort_t* __restrict__ ench1,   // enc_out slices, overwritten by h1(t)
    const ushort_t* __restrict__ wfrag,
    const float* __restrict__ b_ih, const float* __restrict__ b_hh,
    ushort_t* __restrict__ h0s, ushort_t* __restrict__ h1s,
    float* __restrict__ h0f, float* __restrict__ h1f,
    ushort_t* __restrict__ h1_all)               // == ench1
{
  __shared__ float lds_part[32 * 256];  // 32 partial C tiles = 32 KB

  const int tid  = threadIdx.x;
  const int lane = tid & 63;
  const int wid  = tid >> 6;
  const int bid  = blockIdx.x;
  const int layer = bid >> 7;
  const int j0    = (bid & 127) * 8;
  const int mp = wid & 1, g = (wid >> 1) & 1, kh = wid >> 2;
  const int col = lane & 15, kgrp = lane >> 4;
  const bool isL1 = (layer == 1);

  const bool active = isL1 ? (s >= 1) : (s < T_STEPS);
  if (!active) return;  // block-uniform

  // ---- B fragments from pre-packed buffer (coalesced 16B/lane) ----
  const ushort_t* wb = wfrag + ((size_t)bid * 128 + (size_t)g * 64 + (size_t)kh * 32) * 512;
  short8 bfr[2][16];
#pragma unroll
  for (int tl = 0; tl < 2; ++tl)
#pragma unroll
    for (int ko = 0; ko < 16; ++ko)
      bfr[tl][ko] = *(const short8*)(wb + (size_t)(tl * 16 + ko) * 512 + lane * 8);

  const int t = isL1 ? (s - 1) : s;
  const ushort_t* A1 = isL1 ? (h0s + ((s + 1) & 1) * (BATCH * HDIM))
                            : (ench1 + (size_t)t * (BATCH * HDIM));
  const ushort_t* A2 = isL1 ? (h1s + (s & 1) * (BATCH * HDIM))
                            : (h0s + ((s + 1) & 1) * (BATCH * HDIM));
  const ushort_t* A = g ? A2 : A1;

  f32x4 acc00 = {0,0,0,0}, acc01 = {0,0,0,0}, acc10 = {0,0,0,0}, acc11 = {0,0,0,0};
  const ushort_t* Arow0 = A + (size_t)(mp * 32 + col) * HDIM + kh * 512 + kgrp * 8;
  const ushort_t* Arow1 = Arow0 + 16 * HDIM;
#pragma unroll
  for (int ko = 0; ko < 16; ++ko) {
    const short8 a0 = *(const short8*)(Arow0 + ko * 32);
    const short8 a1 = *(const short8*)(Arow1 + ko * 32);
    acc00 = __builtin_amdgcn_mfma_f32_16x16x32_bf16(a0, bfr[0][ko], acc00, 0, 0, 0);
    acc01 = __builtin_amdgcn_mfma_f32_16x16x32_bf16(a0, bfr[1][ko], acc01, 0, 0, 0);
    acc10 = __builtin_amdgcn_mfma_f32_16x16x32_bf16(a1, bfr[0][ko], acc10, 0, 0, 0);
    acc11 = __builtin_amdgcn_mfma_f32_16x16x32_bf16(a1, bfr[1][ko], acc11, 0, 0, 0);
  }
  // publish partials: tile idx = wid*4 + im*2 + tl
  const int base = (wid * 4) * 256 + lane * 4;
  *(f32x4*)&lds_part[base      ] = acc00;
  *(f32x4*)&lds_part[base + 256] = acc01;
  *(f32x4*)&lds_part[base + 512] = acc10;
  *(f32x4*)&lds_part[base + 768] = acc11;

  __syncthreads();

  if (wid < 4) {
    // biases
    float bA = 0.f, bB = 0.f, bC = 0.f;
    {
      const float* bi = b_ih + layer * 3 * HDIM;
      const float* bh = b_hh + layer * 3 * HDIM;
      if (col < 8) {
        const int j = j0 + col;
        bA = bi[j] + bh[j];
        bB = bi[2 * HDIM + j];
        bC = bh[2 * HDIM + j];
      } else {
        const int j = j0 + col - 8;
        bA = bi[HDIM + j] + bh[HDIM + j];
      }
    }

    const int m = wid, mpe = m >> 1, ime = m & 1;
    const int i00 = ((0 * 4 + 0 * 2 + mpe) * 4 + ime * 2);  // ih, kh=0
    const int i01 = ((1 * 4 + 0 * 2 + mpe) * 4 + ime * 2);  // ih, kh=1
    const int i10 = ((0 * 4 + 1 * 2 + mpe) * 4 + ime * 2);  // hh, kh=0
    const int i11 = ((1 * 4 + 1 * 2 + mpe) * 4 + ime * 2);  // hh, kh=1
    const int lo = lane * 4;
    f32x4 girz = *(f32x4*)&lds_part[i00 * 256 + lo] + *(f32x4*)&lds_part[i01 * 256 + lo];
    f32x4 gin  = *(f32x4*)&lds_part[(i00 + 1) * 256 + lo] + *(f32x4*)&lds_part[(i01 + 1) * 256 + lo];
    f32x4 ghrz = *(f32x4*)&lds_part[i10 * 256 + lo] + *(f32x4*)&lds_part[i11 * 256 + lo];
    f32x4 ghn  = *(f32x4*)&lds_part[(i10 + 1) * 256 + lo] + *(f32x4*)&lds_part[(i11 + 1) * 256 + lo];

    const float* hpf = isL1 ? (h1f + (s & 1) * (BATCH * HDIM))
                            : (h0f + ((s + 1) & 1) * (BATCH * HDIM));
    float* hfd       = isL1 ? (h1f + ((s + 1) & 1) * (BATCH * HDIM))
                            : (h0f + (s & 1) * (BATCH * HDIM));
    ushort_t* hdst   = isL1 ? (h1s + ((s + 1) & 1) * (BATCH * HDIM))
                            : (h0s + (s & 1) * (BATCH * HDIM));
    ushort_t* hall   = isL1 ? (h1_all + (size_t)(s - 1) * (BATCH * HDIM)) : (ushort_t*)0;

#pragma unroll
    for (int e = 0; e < 4; ++e) {
      const float rz = sigm(girz[e] + ghrz[e] + bA);            // lo: r, hi: z
      const float nv = tanhf(gin[e] + bB + rz * (ghn[e] + bC)); // valid lo lanes
      const float zv = __shfl_xor(rz, 8);                       // z to lo lanes
      if (col < 8) {
        const int b = m * 16 + kgrp * 4 + e;
        const float hpv = hpf[b * HDIM + j0 + col];
        const float h = (1.f - zv) * nv + zv * hpv;
        hfd[b * HDIM + j0 + col] = h;
        const ushort_t hb = f2bf(h);
        hdst[b * HDIM + j0 + col] = hb;
        if (hall) hall[b * HDIM + j0 + col] = hb;
      }
    }
  }
}

// ---------- decoder: staging = tanh(h1 @ dec_w.T + dec_b), bf16, half-T at a time ----------
__global__ __launch_bounds__(256) void dec_kernel(
    const ushort_t* __restrict__ h1_all, const float* __restrict__ dec_w,
    const float* __restrict__ dec_b, ushort_t* __restrict__ rnn_out)
{
  const int lane = threadIdx.x & 63;
  const int wv   = threadIdx.x >> 6;
  const int cb = blockIdx.x & 15;
  const int rb = blockIdx.x >> 4;
  const int row = rb * 64 + lane;
  const int j0  = cb * 64 + wv * 16;
  const ushort_t* a = h1_all + (size_t)row * HDIM;
  float acc[16];
#pragma unroll
  for (int c = 0; c < 16; ++c) acc[c] = 0.f;

#pragma unroll 1
  for (int k = 0; k < HDIM; k += 8) {
    float af[8];
    uint4 v = *(const uint4*)(a + k);
    unpack8(v, af);
#pragma unroll
    for (int c = 0; c < 16; ++c) {
      const float* wr = dec_w + (size_t)(j0 + c) * HDIM + k;
      dot4(acc[c], af,     *(const float4*)wr);
      dot4(acc[c], af + 4, *(const float4*)(wr + 4));
    }
  }
#pragma unroll
  for (int c = 0; c < 16; ++c) {
    float vq = tanhf(acc[c] + dec_b[j0 + c]);
    rnn_out[(size_t)row * HDIM + j0 + c] = f2bf(vq);
  }
}

// ---------- heads: mean/var for a half-T slab ----------
__global__ __launch_bounds__(256) void head_kernel(
    const ushort_t* __restrict__ rnn_out,
    const float* __restrict__ exp_w, const float* __restrict__ exp_b,
    const float* __restrict__ log_w, const float* __restrict__ log_b,
    float* __restrict__ outm, float* __restrict__ outv)
{
  const int lane = threadIdx.x & 63;
  const int wv   = threadIdx.x >> 6;
  const int row = blockIdx.x * 64 + lane;
  const int c0  = wv * 32;
  const ushort_t* a = rnn_out + (size_t)row * HDIM;
  const float* wmat = (c0 < 64) ? exp_w : log_w;
  const int cc0 = c0 & 63;

  float acc[32];
#pragma unroll
  for (int i = 0; i < 32; ++i) acc[i] = 0.f;

#pragma unroll 1
  for (int k = 0; k < HDIM; k += 8) {
    float af[8];
    uint4 v = *(const uint4*)(a + k);
    unpack8(v, af);
#pragma unroll
    for (int i = 0; i < 32; ++i) {
      const float* wr = wmat + (size_t)(cc0 + i) * HDIM + k;
      dot4(acc[i], af,     *(const float4*)wr);
      dot4(acc[i], af + 4, *(const float4*)(wr + 4));
    }
  }

  if (c0 < 64) {
#pragma unroll
    for (int i = 0; i < 32; ++i) {
      int y = cc0 + i;
      outm[(size_t)row * YDIM + y] = acc[i] + exp_b[y];
    }
  } else {
#pragma unroll
    for (int i = 0; i < 32; ++i) {
      int y = cc0 + i;
      outv[(size_t)row * YDIM + y] = expf(acc[i] + log_b[y]);
    }
  }
}

// ---------- host ----------
extern "C" void kernel_launch(void* const* d_in, const int* in_sizes, int n_in,
                              void* d_out, int out_size, void* d_ws, size_t ws_size,
                              hipStream_t stream) {
  (void)in_sizes; (void)n_in; (void)out_size; (void)ws_size;
  const float* x     = (const float*)d_in[0];
  const float* enc_w = (const float*)d_in[1];
  const float* enc_b = (const float*)d_in[2];
  const float* w_ih  = (const float*)d_in[3];
  const float* w_hh  = (const float*)d_in[4];
  const float* b_ih  = (const float*)d_in[5];
  const float* b_hh  = (const float*)d_in[6];
  const float* dec_w = (const float*)d_in[7];
  const float* dec_b = (const float*)d_in[8];
  const float* exp_w = (const float*)d_in[9];
  const float* exp_b = (const float*)d_in[10];
  const float* log_w = (const float*)d_in[11];
  const float* log_b = (const float*)d_in[12];
  float* out = (float*)d_out;

  char* ws = (char*)d_ws;
  ushort_t* h0s   = (ushort_t*)ws;                       // 2x[64][1024] bf16 = 256 KB
  ushort_t* h1s   = (ushort_t*)(ws + 262144);            // 256 KB
  float*    h0f   = (float*)(ws + 524288);               // 2x[64][1024] f32 = 512 KB
  float*    h1f   = (float*)(ws + 1048576);              // 512 KB
  ushort_t* wfrag = (ushort_t*)(ws + 2097152);           // 32 MB (reused as rnn_out staging)
  ushort_t* ench1 = (ushort_t*)(ws + 2097152 + 33554432);// 64 MB: enc_out, overwritten by h1_all

  hipMemsetAsync(ws, 0, 1572864, stream);  // zero h-state buffers (bf16 + f32)

  enc_kernel<<<32768, 256, 0, stream>>>(x, enc_w, enc_b, ench1);
  wprep_kernel<<<8192, 256, 0, stream>>>(w_ih, w_hh, wfrag);

  for (int s = 0; s <= T_STEPS; ++s)
    step_kernel<<<256, 512, 0, stream>>>(s, ench1, wfrag, b_ih, b_hh,
                                         h0s, h1s, h0f, h1f, ench1);

  // dec + heads in two half-T passes, staging rnn_out in the (now dead) wfrag area
  ushort_t* staging = wfrag;  // 16384 rows x 1024 bf16 = 32 MB
  for (int half = 0; half < 2; ++half) {
    const ushort_t* h1p = ench1 + (size_t)half * 16384 * HDIM;
    dec_kernel<<<4096, 256, 0, stream>>>(h1p, dec_w, dec_b, staging);
    float* outm = out + (size_t)half * 16384 * YDIM;
    float* outv = out + (size_t)T_STEPS * BATCH * YDIM + (size_t)half * 16384 * YDIM;
    head_kernel<<<256, 256, 0, stream>>>(staging, exp_w, exp_b, log_w, log_b, outm, outv);
  }
}